// Round 2
// baseline (2134.518 us; speedup 1.0000x reference)
//
#include <hip/hip_runtime.h>
#include <math.h>

// VQ: x [32,256,32,32] fp32, codebook [8192,256] fp32.
// Point n=(b,w,h): f[c] = x[b,c,h,w].  argmin_k (||f||^2 - 2 f.c_k + ||c_k||^2),
// computed with np's association: (fn + (-2 f.c)) + cn.
// Outputs: codes [32,256,32,32] fp32 then indices [32,32,32] (as float) in d_out.

#define KC 8192
#define DD 256
#define BN 64
#define BK 128
#define KK 16
#define NSLICE ((KC / BK) * (DD / KK)) // 1024

__global__ __launch_bounds__(256) void cnorm_k(const float4* __restrict__ cb4,
                                               float* __restrict__ cn) {
  int lane = threadIdx.x & 63;
  int row = (blockIdx.x << 2) + (threadIdx.x >> 6); // 4 waves/block, 1 row/wave
  float4 v = cb4[(size_t)row * 64 + lane];
  float s = v.x * v.x + v.y * v.y + v.z * v.z + v.w * v.w;
#pragma unroll
  for (int off = 32; off > 0; off >>= 1) s += __shfl_xor(s, off, 64);
  if (lane == 0) cn[row] = s;
}

__global__ void __launch_bounds__(256, 2) vq_main(const float* __restrict__ x,
                                                  const float4* __restrict__ cb4,
                                                  const float4* __restrict__ cn4,
                                                  float* __restrict__ out) {
  __shared__ float Fs[DD][BN];       // 64 KB, stores -2*x, c-major
  __shared__ float Bs[2][KK][BK];    // 16 KB, double-buffered codebook c-slice

  const int tid = threadIdx.x;
  const int b = blockIdx.x >> 4;          // 0..31
  const int h0 = (blockIdx.x & 15) << 1;  // 0,2,..,30 ; points: h in {h0,h0+1}, w 0..31

  // ---- stage Fs = -2*x  (point i = (h-h0)*32 + w -> contiguous 64 floats per c)
  {
    const float4* x4 = (const float4*)x + ((size_t)b << 16) + (h0 << 3);
    const int cl = tid >> 4;  // 0..15
    const int q = tid & 15;   // float4 col within 64-float row
#pragma unroll
    for (int p = 0; p < 16; ++p) {
      int c = (p << 4) + cl;
      float4 v = x4[(size_t)c * 256 + q];   // channel stride = 1024 floats = 256 float4
      float4* dst = (float4*)&Fs[c][q << 2];
      *dst = make_float4(-2.f * v.x, -2.f * v.y, -2.f * v.z, -2.f * v.w);
    }
  }

  // ---- prologue: stage slice 0 into Bs[0]
  const int sk = tid >> 1;              // code row 0..127
  const int sfc = (tid & 1) << 1;       // f4 col pair base (0 or 2)
  float4 rb0, rb1;
  {
    rb0 = cb4[(size_t)sk * 64 + sfc];
    rb1 = cb4[(size_t)sk * 64 + sfc + 1];
    int cbase = sfc << 2;
    Bs[0][cbase + 0][sk] = rb0.x; Bs[0][cbase + 1][sk] = rb0.y;
    Bs[0][cbase + 2][sk] = rb0.z; Bs[0][cbase + 3][sk] = rb0.w;
    Bs[0][cbase + 4][sk] = rb1.x; Bs[0][cbase + 5][sk] = rb1.y;
    Bs[0][cbase + 6][sk] = rb1.z; Bs[0][cbase + 7][sk] = rb1.w;
  }
  __syncthreads();

  const int tr = tid & 15;  // point group: points 4tr..4tr+3
  const int tc = tid >> 4;  // code group: codes 8tc..8tc+7 within tile

  // ---- per-point ||f||^2 = 0.25 * sum Fs^2  (exact: Fs = -2x, /4 is exact)
  float fn[4];
  {
    float f0 = 0.f, f1 = 0.f, f2 = 0.f, f3 = 0.f;
#pragma unroll 8
    for (int c = 0; c < DD; ++c) {
      float4 v = *(const float4*)&Fs[c][tr << 2];
      f0 += v.x * v.x; f1 += v.y * v.y; f2 += v.z * v.z; f3 += v.w * v.w;
    }
    fn[0] = 0.25f * f0; fn[1] = 0.25f * f1; fn[2] = 0.25f * f2; fn[3] = 0.25f * f3;
  }

  float mn[4] = {INFINITY, INFINITY, INFINITY, INFINITY};
  int id[4] = {0, 0, 0, 0};
  float acc[4][8];
  float cnv[8];

  for (int t = 0; t < NSLICE; ++t) {
    const int cur = t & 1;
    const int cs = t & 15;   // c-slice within tile
    const int ct = t >> 4;   // code tile

    // issue next slice's global loads (hidden under 512 FMAs)
    if (t + 1 < NSLICE) {
      const int tn = t + 1;
      const size_t k0 = (size_t)(tn >> 4) << 7;
      const int c0f4 = (tn & 15) << 2;
      rb0 = cb4[(k0 + sk) * 64 + c0f4 + sfc];
      rb1 = cb4[(k0 + sk) * 64 + c0f4 + sfc + 1];
    }

    if (cs == 0) {
      float4 c0 = cn4[(ct << 5) + (tc << 1)];
      float4 c1 = cn4[(ct << 5) + (tc << 1) + 1];
      cnv[0] = c0.x; cnv[1] = c0.y; cnv[2] = c0.z; cnv[3] = c0.w;
      cnv[4] = c1.x; cnv[5] = c1.y; cnv[6] = c1.z; cnv[7] = c1.w;
#pragma unroll
      for (int ii = 0; ii < 4; ++ii)
#pragma unroll
        for (int jj = 0; jj < 8; ++jj) acc[ii][jj] = 0.f;
    }

#pragma unroll
    for (int cl = 0; cl < KK; ++cl) {
      const float4 av = *(const float4*)&Fs[(cs << 4) + cl][tr << 2];
      const float4 b0 = *(const float4*)&Bs[cur][cl][tc << 3];
      const float4 b1 = *(const float4*)&Bs[cur][cl][(tc << 3) + 4];
      const float a[4] = {av.x, av.y, av.z, av.w};
      const float bb[8] = {b0.x, b0.y, b0.z, b0.w, b1.x, b1.y, b1.z, b1.w};
#pragma unroll
      for (int ii = 0; ii < 4; ++ii)
#pragma unroll
        for (int jj = 0; jj < 8; ++jj) acc[ii][jj] += a[ii] * bb[jj];
    }

    if (cs == 15) {
      const int kb = (ct << 7) + (tc << 3);
#pragma unroll
      for (int ii = 0; ii < 4; ++ii)
#pragma unroll
        for (int jj = 0; jj < 8; ++jj) {
          // np association: (fn - 2 f.c) + cn
          float s = (fn[ii] + acc[ii][jj]) + cnv[jj];
          if (s < mn[ii]) { mn[ii] = s; id[ii] = kb + jj; }
        }
    }

    if (t + 1 < NSLICE) {
      const int nb = (t + 1) & 1;
      const int cbase = sfc << 2;
      Bs[nb][cbase + 0][sk] = rb0.x; Bs[nb][cbase + 1][sk] = rb0.y;
      Bs[nb][cbase + 2][sk] = rb0.z; Bs[nb][cbase + 3][sk] = rb0.w;
      Bs[nb][cbase + 4][sk] = rb1.x; Bs[nb][cbase + 5][sk] = rb1.y;
      Bs[nb][cbase + 6][sk] = rb1.z; Bs[nb][cbase + 7][sk] = rb1.w;
    }
    __syncthreads();
  }

  // ---- cross-thread argmin reduction (16 tc groups per point), reuse Bs storage
  float* mred = &Bs[0][0][0];        // 1024 floats
  int* ired = (int*)(mred + 1024);   // 1024 ints
  int* fin = (int*)(mred + 2048);    // 64 ints
#pragma unroll
  for (int ii = 0; ii < 4; ++ii) {
    mred[(tc << 6) + (tr << 2) + ii] = mn[ii];
    ired[(tc << 6) + (tr << 2) + ii] = id[ii];
  }
  __syncthreads();
  if (tid < 64) {
    float bm = mred[tid];
    int bi = ired[tid];
    for (int tcc = 1; tcc < 16; ++tcc) {
      float v = mred[(tcc << 6) + tid];
      int iv = ired[(tcc << 6) + tid];
      // np.argmin tie-break: first occurrence = lowest index
      if (v < bm || (v == bm && iv < bi)) { bm = v; bi = iv; }
    }
    fin[tid] = bi;
    // indices output (as float), offset = 32*256*32*32
    out[(size_t)8388608 + ((size_t)b << 10) + (h0 << 5) + tid] = (float)bi;
  }
  __syncthreads();

  // ---- codes gather: out[b,c,h,w] = codebook[idx][c]
  {
    const int i = tid & 63;
    const int cg = tid >> 6;  // 0..3
    const int code = fin[i];
    const float4* cbr = cb4 + (size_t)code * 64;
    const size_t obase = ((size_t)b << 18) + (h0 << 5) + i;
#pragma unroll
    for (int cc = 0; cc < 16; ++cc) {
      int c4 = (cc << 2) + cg;
      float4 v = cbr[c4];
      out[obase + (size_t)(c4 * 4 + 0) * 1024] = v.x;
      out[obase + (size_t)(c4 * 4 + 1) * 1024] = v.y;
      out[obase + (size_t)(c4 * 4 + 2) * 1024] = v.z;
      out[obase + (size_t)(c4 * 4 + 3) * 1024] = v.w;
    }
  }
}

extern "C" void kernel_launch(void* const* d_in, const int* in_sizes, int n_in,
                              void* d_out, int out_size, void* d_ws, size_t ws_size,
                              hipStream_t stream) {
  const float* x = (const float*)d_in[0];
  const float* cb = (const float*)d_in[1];
  float* out = (float*)d_out;
  float* cnorm = (float*)d_ws;  // 8192 floats

  cnorm_k<<<KC / 4, 256, 0, stream>>>((const float4*)cb, cnorm);
  vq_main<<<512, 256, 0, stream>>>(x, (const float4*)cb, (const float4*)cnorm, out);
}

// Round 3
// 900.292 us; speedup vs baseline: 2.3709x; 2.3709x over previous
//
#include <hip/hip_runtime.h>
#include <math.h>

// VQ via split-fp16 MFMA emulation of fp32 GEMM.
// x [32,256,32,32] f32, codebook [8192,256] f32.
// d2 = (||f||^2 - 2 f.c) + ||c||^2, argmin over 8192 codes, np association.
// f.c computed as 2^-26 * MFMA( h/m split of 8192*f, 8192*c ): products hh+hm+mh.
// Outputs: codes [32,256,32,32] f32 then indices [32,32,32] (as float).

typedef _Float16 v8h __attribute__((ext_vector_type(8)));
typedef float f32x16 __attribute__((ext_vector_type(16)));
typedef unsigned int u32;

#define MFMA16 __builtin_amdgcn_mfma_f32_32x32x16_f16

__global__ __launch_bounds__(256) void cnorm_k(const float4* __restrict__ cb4,
                                               float* __restrict__ cn) {
  int lane = threadIdx.x & 63;
  int row = (blockIdx.x << 2) + (threadIdx.x >> 6);
  float4 v = cb4[(size_t)row * 64 + lane];
  float s = v.x * v.x + v.y * v.y + v.z * v.z + v.w * v.w;
#pragma unroll
  for (int off = 32; off > 0; off >>= 1) s += __shfl_xor(s, off, 64);
  if (lane == 0) cn[row] = s;
}

__global__ void __launch_bounds__(512, 2) vq_mfma(const float* __restrict__ x,
                                                  const float4* __restrict__ cb4,
                                                  const float* __restrict__ cn,
                                                  float* __restrict__ out) {
  // F2: point splits [ver][pt][ch], rows padded 256->264 (33*16B: conflict-free b128)
  __shared__ __align__(16) _Float16 F2[2][64][264];   // 67,584 B
  // Bsh: code rows [h 0..31 | m 32..63 | pad ->72] fp16 (144B = 9*16B rows)
  __shared__ __align__(16) _Float16 Bsh[512][72];     // 73,728 B
  __shared__ float fnP[64][8];
  __shared__ float fnS[64];
  __shared__ float wredS[8][64];
  __shared__ u32  wredC[8][64];
  __shared__ u32  finS[64];

  const int tid = threadIdx.x;
  const int lane = tid & 63;
  const int w = tid >> 6;        // wave 0..7: codes [w*64, w*64+64) within tile
  const int col = lane & 31;
  const int hi = lane >> 5;
  const int b = blockIdx.x >> 4;
  const int h0 = (blockIdx.x & 15) << 1;

  float4 rg[8];
  { // issue global loads for staging step 0 (code=tid, ch 0..31)
    const float4* src = cb4 + ((size_t)tid << 6);
#pragma unroll
    for (int j = 0; j < 8; ++j) rg[j] = src[j];
  }

  // ---- phase 0: stage F splits (scaled by 2^13) + fn partials
  {
    const float* xb = x + ((size_t)b << 18) + (h0 << 5);
    float s = 0.f;
#pragma unroll
    for (int j = 0; j < 4; ++j) {
      v8h hv, mv;
#pragma unroll
      for (int i = 0; i < 8; ++i) {
        const int c = (w << 5) + (j << 3) + i;
        float v = xb[(size_t)c * 1024 + lane];   // coalesced: lane = point
        s += v * v;
        float vs = v * 8192.f;
        _Float16 h = (_Float16)vs;
        _Float16 m = (_Float16)(vs - (float)h);
        hv[i] = h; mv[i] = m;
      }
      *(v8h*)&F2[0][lane][(w << 5) + (j << 3)] = hv;
      *(v8h*)&F2[1][lane][(w << 5) + (j << 3)] = mv;
    }
    fnP[lane][w] = s;
  }
  __syncthreads();
  if (tid < 64) {
    float t = 0.f;
#pragma unroll
    for (int j = 0; j < 8; ++j) t += fnP[tid][j];
    fnS[tid] = t;
  }
  { // convert + write Bs for step 0 (nobody reads Bsh before next barrier)
#pragma unroll
    for (int j = 0; j < 4; ++j) {
      float t0[8] = {rg[2*j].x, rg[2*j].y, rg[2*j].z, rg[2*j].w,
                     rg[2*j+1].x, rg[2*j+1].y, rg[2*j+1].z, rg[2*j+1].w};
      v8h hv, mv;
#pragma unroll
      for (int i = 0; i < 8; ++i) {
        float vs = t0[i] * 8192.f;
        _Float16 h = (_Float16)vs;
        _Float16 m = (_Float16)(vs - (float)h);
        hv[i] = h; mv[i] = m;
      }
      *(v8h*)&Bsh[tid][(j << 3)] = hv;
      *(v8h*)&Bsh[tid][32 + (j << 3)] = mv;
    }
  }
  __syncthreads();

  // fn per slot (row = Mb*32 + (reg&3) + (reg>>2)*8 + hi*4)
  float fnr[32];
#pragma unroll
  for (int sl = 0; sl < 32; ++sl) {
    const int row = ((sl >> 4) << 5) + (sl & 3) + (((sl >> 2) & 3) << 3) + (hi << 2);
    fnr[sl] = fnS[row];
  }

  f32x16 acc[2][2];
#pragma unroll
  for (int r = 0; r < 16; ++r) {
    acc[0][0][r] = 0.f; acc[0][1][r] = 0.f; acc[1][0][r] = 0.f; acc[1][1][r] = 0.f;
  }
  float mn[32];
#pragma unroll
  for (int sl = 0; sl < 32; ++sl) mn[sl] = INFINITY;
  u32 idp[8] = {0, 0, 0, 0, 0, 0, 0, 0};
  float cnv0 = 0.f, cnv1 = 0.f;

  // ---- main loop: 16 code tiles (512 codes) x 8 k-steps (32 ch)
  for (int st = 0; st < 128; ++st) {
    const int ks = st & 7, ct = st >> 3;
    if (st < 127) {
      const int tn = st + 1;
      const float4* src = cb4 + ((size_t)((((tn >> 3) << 9) + tid)) << 6) + ((tn & 7) << 3);
#pragma unroll
      for (int j = 0; j < 8; ++j) rg[j] = src[j];
    }
    if (ks == 0) {
      cnv0 = cn[(ct << 9) + (w << 6) + col];
      cnv1 = cn[(ct << 9) + (w << 6) + 32 + col];
    }

    const int kb = ks << 5;
#pragma unroll
    for (int kh = 0; kh < 2; ++kh) {
      const int ko = kb + (kh << 4) + (hi << 3);
      const v8h ah0 = *(const v8h*)&F2[0][col][ko];
      const v8h ah1 = *(const v8h*)&F2[0][32 + col][ko];
      const v8h am0 = *(const v8h*)&F2[1][col][ko];
      const v8h am1 = *(const v8h*)&F2[1][32 + col][ko];
      const int bo = (kh << 4) + (hi << 3);
      const v8h bh0 = *(const v8h*)&Bsh[(w << 6) + col][bo];
      const v8h bh1 = *(const v8h*)&Bsh[(w << 6) + 32 + col][bo];
      const v8h bm0 = *(const v8h*)&Bsh[(w << 6) + col][32 + bo];
      const v8h bm1 = *(const v8h*)&Bsh[(w << 6) + 32 + col][32 + bo];
      acc[0][0] = MFMA16(ah0, bh0, acc[0][0], 0, 0, 0);
      acc[0][0] = MFMA16(ah0, bm0, acc[0][0], 0, 0, 0);
      acc[0][0] = MFMA16(am0, bh0, acc[0][0], 0, 0, 0);
      acc[0][1] = MFMA16(ah0, bh1, acc[0][1], 0, 0, 0);
      acc[0][1] = MFMA16(ah0, bm1, acc[0][1], 0, 0, 0);
      acc[0][1] = MFMA16(am0, bh1, acc[0][1], 0, 0, 0);
      acc[1][0] = MFMA16(ah1, bh0, acc[1][0], 0, 0, 0);
      acc[1][0] = MFMA16(ah1, bm0, acc[1][0], 0, 0, 0);
      acc[1][0] = MFMA16(am1, bh0, acc[1][0], 0, 0, 0);
      acc[1][1] = MFMA16(ah1, bh1, acc[1][1], 0, 0, 0);
      acc[1][1] = MFMA16(ah1, bm1, acc[1][1], 0, 0, 0);
      acc[1][1] = MFMA16(am1, bh1, acc[1][1], 0, 0, 0);
    }

    if (ks == 7) { // tile epilogue: s = (fn - 2*dot) + cn, running argmin
#pragma unroll
      for (int sl = 0; sl < 32; ++sl) {
        const int Mb = sl >> 4, reg = sl & 15;
        const float base = fnr[sl];
        const u32 sh = (u32)((sl & 3) << 3);
        {
          float s = (base + (-0x1p-25f) * acc[Mb][0][reg]) + cnv0;
          const bool better = s < mn[sl];
          const u32 cur = idp[sl >> 2];
          const u32 upd = (cur & ~(255u << sh)) | (((u32)(ct << 1)) << sh);
          idp[sl >> 2] = better ? upd : cur;
          mn[sl] = better ? s : mn[sl];
        }
        {
          float s = (base + (-0x1p-25f) * acc[Mb][1][reg]) + cnv1;
          const bool better = s < mn[sl];
          const u32 cur = idp[sl >> 2];
          const u32 upd = (cur & ~(255u << sh)) | (((u32)((ct << 1) | 1)) << sh);
          idp[sl >> 2] = better ? upd : cur;
          mn[sl] = better ? s : mn[sl];
        }
      }
#pragma unroll
      for (int r = 0; r < 16; ++r) {
        acc[0][0][r] = 0.f; acc[0][1][r] = 0.f; acc[1][0][r] = 0.f; acc[1][1][r] = 0.f;
      }
    }

    // convert next slice (VALU, overlaps nothing serial; rg arrived during MFMAs)
    v8h cr[8];
    if (st < 127) {
#pragma unroll
      for (int j = 0; j < 4; ++j) {
        float t0[8] = {rg[2*j].x, rg[2*j].y, rg[2*j].z, rg[2*j].w,
                       rg[2*j+1].x, rg[2*j+1].y, rg[2*j+1].z, rg[2*j+1].w};
#pragma unroll
        for (int i = 0; i < 8; ++i) {
          float vs = t0[i] * 8192.f;
          _Float16 h = (_Float16)vs;
          _Float16 m = (_Float16)(vs - (float)h);
          cr[j][i] = h; cr[4 + j][i] = m;
        }
      }
    }
    __syncthreads();           // all reads of Bsh(st) done
    if (st < 127) {
#pragma unroll
      for (int j = 0; j < 4; ++j) {
        *(v8h*)&Bsh[tid][(j << 3)] = cr[j];
        *(v8h*)&Bsh[tid][32 + (j << 3)] = cr[4 + j];
      }
    }
    __syncthreads();           // Bsh(st+1) visible
  }

  // ---- final reduction: per-slot butterfly over 32 col-lanes, then cross-wave
#pragma unroll
  for (int sl = 0; sl < 32; ++sl) {
    float v = mn[sl];
    const u32 byte = (idp[sl >> 2] >> ((sl & 3) << 3)) & 255u;
    u32 code = ((byte >> 1) << 9) + ((u32)w << 6) + ((byte & 1) << 5) + (u32)col;
#pragma unroll
    for (int off = 1; off < 32; off <<= 1) {
      float v2 = __shfl_xor(v, off, 64);
      u32 c2 = (u32)__shfl_xor((int)code, off, 64);
      if (v2 < v || (v2 == v && c2 < code)) { v = v2; code = c2; }
    }
    if (col == 0) {
      const int row = ((sl >> 4) << 5) + (sl & 3) + (((sl >> 2) & 3) << 3) + (hi << 2);
      wredS[w][row] = v; wredC[w][row] = code;
    }
  }
  __syncthreads();
  if (tid < 64) {
    float bv = wredS[0][tid]; u32 bc = wredC[0][tid];
#pragma unroll
    for (int j = 1; j < 8; ++j) {
      float vv = wredS[j][tid]; u32 cc = wredC[j][tid];
      if (vv < bv || (vv == bv && cc < bc)) { bv = vv; bc = cc; }
    }
    finS[tid] = bc;
    out[(size_t)8388608 + ((size_t)b << 10) + (h0 << 5) + tid] = (float)bc;
  }
  __syncthreads();

  // ---- codes gather: out[b,c,h,w] = codebook[idx][c]
  {
    const int pt = tid & 63, cg = tid >> 6;
    const u32 code = finS[pt];
    const float4* cbr = cb4 + ((size_t)code << 6);
    const size_t obase = ((size_t)b << 18) + (h0 << 5) + pt;
#pragma unroll
    for (int cc = 0; cc < 8; ++cc) {
      const int c4 = (cc << 3) + cg;
      float4 vv = cbr[c4];
      out[obase + (size_t)((c4 << 2) + 0) * 1024] = vv.x;
      out[obase + (size_t)((c4 << 2) + 1) * 1024] = vv.y;
      out[obase + (size_t)((c4 << 2) + 2) * 1024] = vv.z;
      out[obase + (size_t)((c4 << 2) + 3) * 1024] = vv.w;
    }
  }
}

extern "C" void kernel_launch(void* const* d_in, const int* in_sizes, int n_in,
                              void* d_out, int out_size, void* d_ws, size_t ws_size,
                              hipStream_t stream) {
  const float* x = (const float*)d_in[0];
  const float* cb = (const float*)d_in[1];
  float* out = (float*)d_out;
  float* cnorm = (float*)d_ws;  // 8192 floats

  cnorm_k<<<2048, 256, 0, stream>>>((const float4*)cb, cnorm);
  vq_mfma<<<512, 512, 0, stream>>>(x, (const float4*)cb, cnorm, out);
}

// Round 4
// 607.971 us; speedup vs baseline: 3.5109x; 1.4808x over previous
//
#include <hip/hip_runtime.h>
#include <math.h>

// VQ via split-fp16 MFMA emulation of fp32 GEMM, with pre-split pre-permuted
// codebook staged by global_load_lds (dbuf, 1 barrier/step).
// x [32,256,32,32] f32, codebook [8192,256] f32.
// d2 = (||f||^2 - 2 f.c) + ||c||^2, argmin over 8192 codes, np association.
// f.c = 2^-26 * MFMA(h/m split of 8192*f, 8192*c): products hh+hm+mh.
// Outputs: codes [32,256,32,32] f32 then indices [32,32,32] (as float).

typedef _Float16 v8h __attribute__((ext_vector_type(8)));
typedef float f32x16 __attribute__((ext_vector_type(16)));
typedef unsigned int u32;

#define MFMA16 __builtin_amdgcn_mfma_f32_32x32x16_f16

__device__ __forceinline__ void gll16(const _Float16* g, _Float16* l) {
  __builtin_amdgcn_global_load_lds(
      (const __attribute__((address_space(1))) void*)(const void*)g,
      (__attribute__((address_space(3))) void*)(void*)l, 16, 0, 0);
}

__global__ __launch_bounds__(256) void cnorm_k(const float4* __restrict__ cb4,
                                               float* __restrict__ cn) {
  int lane = threadIdx.x & 63;
  int row = (blockIdx.x << 2) + (threadIdx.x >> 6);
  float4 v = cb4[(size_t)row * 64 + lane];
  float s = v.x * v.x + v.y * v.y + v.z * v.z + v.w * v.w;
#pragma unroll
  for (int off = 32; off > 0; off >>= 1) s += __shfl_xor(s, off, 64);
  if (lane == 0) cn[row] = s;
}

// Pre-split codebook into h/m fp16 planes, permuted so each (ct,ks) 32KB tile is
// the EXACT linear LDS image: halves[((pl*2+hi)*512 + code)*8 + i],
// value = plane of 8192*cb[ct*512+code][ks*16+hi*8+i].
__global__ __launch_bounds__(256) void split_cb(const float4* __restrict__ cb4,
                                                _Float16* __restrict__ W) {
  const int j = threadIdx.x & 31;
  const int ks = j >> 1, hi = j & 1;
  const int r = (blockIdx.x << 3) + (threadIdx.x >> 5);  // code row 0..8191
  const float4* src = cb4 + (size_t)r * 64 + (ks << 2) + (hi << 1);
  float4 v0 = src[0], v1 = src[1];
  float t[8] = {v0.x, v0.y, v0.z, v0.w, v1.x, v1.y, v1.z, v1.w};
  v8h hv, mv;
#pragma unroll
  for (int i = 0; i < 8; ++i) {
    float vs = t[i] * 8192.f;
    _Float16 h = (_Float16)vs;
    _Float16 m = (_Float16)(vs - (float)h);
    hv[i] = h; mv[i] = m;
  }
  const int code = r & 511;
  _Float16* base = W + ((size_t)((r >> 9) << 4) + ks) * 16384;  // tile = ct*16+ks
  *(v8h*)(base + (((hi << 9) + code) << 3)) = hv;                // pl=0
  *(v8h*)(base + ((1024 + (hi << 9) + code) << 3)) = mv;         // pl=1
}

__global__ void __launch_bounds__(512, 2) vq_fast(const float* __restrict__ x,
                                                  const float4* __restrict__ cb4,
                                                  const float* __restrict__ cn,
                                                  const _Float16* __restrict__ W,
                                                  float* __restrict__ out) {
  __shared__ __align__(16) _Float16 F2[2][64][264];   // 67,584 B: -2x splits, padded
  __shared__ __align__(16) _Float16 Bsh[2][16384];    // 65,536 B: dbuf B tiles
  __shared__ float fnP[64][8];
  __shared__ float fnS[64];
  __shared__ float wredS[8][64];
  __shared__ u32  wredC[8][64];
  __shared__ u32  finS[64];

  const int tid = threadIdx.x;
  const int lane = tid & 63;
  const int w = tid >> 6;
  const int col = lane & 31;
  const int hi = lane >> 5;
  const int b = blockIdx.x >> 4;
  const int h0 = (blockIdx.x & 15) << 1;

  // ---- prologue: async-stage tile 0 into Bsh[0] (latency hides under F staging)
  {
    const _Float16* src = W + (w << 11) + (lane << 3);
    _Float16* dst = &Bsh[0][w << 11];
#pragma unroll
    for (int i = 0; i < 4; ++i) gll16(src + (i << 9), dst + (i << 9));
  }

  // ---- stage F splits (scaled by 2^13) + fn partials
  {
    const float* xb = x + ((size_t)b << 18) + (h0 << 5);
    float s = 0.f;
#pragma unroll
    for (int j = 0; j < 4; ++j) {
      v8h hv, mv;
#pragma unroll
      for (int i = 0; i < 8; ++i) {
        const int c = (w << 5) + (j << 3) + i;
        float v = xb[(size_t)c * 1024 + lane];   // coalesced: lane = point
        s += v * v;
        float vs = v * 8192.f;
        _Float16 h = (_Float16)vs;
        _Float16 m = (_Float16)(vs - (float)h);
        hv[i] = h; mv[i] = m;
      }
      *(v8h*)&F2[0][lane][(w << 5) + (j << 3)] = hv;
      *(v8h*)&F2[1][lane][(w << 5) + (j << 3)] = mv;
    }
    fnP[lane][w] = s;
  }
  __syncthreads();   // F2 + fnP visible; gll(tile 0) drained
  if (tid < 64) {
    float t = 0.f;
#pragma unroll
    for (int j = 0; j < 8; ++j) t += fnP[tid][j];
    fnS[tid] = t;
  }
  __syncthreads();

  // fn per slot (row = Mb*32 + (reg&3) + ((reg>>2)&3)*8 + hi*4)
  float fnr[32];
#pragma unroll
  for (int sl = 0; sl < 32; ++sl) {
    const int row = ((sl >> 4) << 5) + (sl & 3) + (((sl >> 2) & 3) << 3) + (hi << 2);
    fnr[sl] = fnS[row];
  }

  f32x16 acc[2][2];
#pragma unroll
  for (int r = 0; r < 16; ++r) {
    acc[0][0][r] = 0.f; acc[0][1][r] = 0.f; acc[1][0][r] = 0.f; acc[1][1][r] = 0.f;
  }
  float mn[32];
#pragma unroll
  for (int sl = 0; sl < 32; ++sl) mn[sl] = INFINITY;
  u32 idp[8] = {0, 0, 0, 0, 0, 0, 0, 0};
  float cnv0 = 0.f, cnv1 = 0.f;

  const int cbase = (w << 6) + col;

  // ---- main loop: 16 code tiles (512 codes) x 16 k-steps (16 ch), dbuf
  for (int st = 0; st < 256; ++st) {
    const int ks = st & 15, ct = st >> 4, cur = st & 1;

    // prefetch next tile into the other buffer (consumed 2 steps ago -> free)
    if (st < 255) {
      const _Float16* src = W + ((size_t)(st + 1) << 14) + (w << 11) + (lane << 3);
      _Float16* dst = &Bsh[cur ^ 1][w << 11];
#pragma unroll
      for (int i = 0; i < 4; ++i) gll16(src + (i << 9), dst + (i << 9));
    }
    if (ks == 0) {
      cnv0 = cn[(ct << 9) + (w << 6) + col];
      cnv1 = cn[(ct << 9) + (w << 6) + 32 + col];
    }

    const int ko = (ks << 4) + (hi << 3);
    const v8h ah0 = *(const v8h*)&F2[0][col][ko];
    const v8h ah1 = *(const v8h*)&F2[0][32 + col][ko];
    const v8h am0 = *(const v8h*)&F2[1][col][ko];
    const v8h am1 = *(const v8h*)&F2[1][32 + col][ko];
    const _Float16* Bb = Bsh[cur];
    const v8h bh0 = *(const v8h*)&Bb[((hi << 9) + cbase) << 3];
    const v8h bh1 = *(const v8h*)&Bb[((hi << 9) + cbase + 32) << 3];
    const v8h bm0 = *(const v8h*)&Bb[(1024 + (hi << 9) + cbase) << 3];
    const v8h bm1 = *(const v8h*)&Bb[(1024 + (hi << 9) + cbase + 32) << 3];

    acc[0][0] = MFMA16(ah0, bh0, acc[0][0], 0, 0, 0);
    acc[0][0] = MFMA16(ah0, bm0, acc[0][0], 0, 0, 0);
    acc[0][0] = MFMA16(am0, bh0, acc[0][0], 0, 0, 0);
    acc[0][1] = MFMA16(ah0, bh1, acc[0][1], 0, 0, 0);
    acc[0][1] = MFMA16(ah0, bm1, acc[0][1], 0, 0, 0);
    acc[0][1] = MFMA16(am0, bh1, acc[0][1], 0, 0, 0);
    acc[1][0] = MFMA16(ah1, bh0, acc[1][0], 0, 0, 0);
    acc[1][0] = MFMA16(ah1, bm0, acc[1][0], 0, 0, 0);
    acc[1][0] = MFMA16(am1, bh0, acc[1][0], 0, 0, 0);
    acc[1][1] = MFMA16(ah1, bh1, acc[1][1], 0, 0, 0);
    acc[1][1] = MFMA16(ah1, bm1, acc[1][1], 0, 0, 0);
    acc[1][1] = MFMA16(am1, bh1, acc[1][1], 0, 0, 0);

    if (ks == 15) {  // tile epilogue: s = (fn - 2*dot) + cn, running argmin
#pragma unroll
      for (int sl = 0; sl < 32; ++sl) {
        const int Mb = sl >> 4, reg = sl & 15;
        const float base = fnr[sl];
        const u32 sh = (u32)((sl & 3) << 3);
        {
          float s = (base + (-0x1p-25f) * acc[Mb][0][reg]) + cnv0;
          const bool better = s < mn[sl];
          const u32 curv = idp[sl >> 2];
          const u32 upd = (curv & ~(255u << sh)) | (((u32)(ct << 1)) << sh);
          idp[sl >> 2] = better ? upd : curv;
          mn[sl] = better ? s : mn[sl];
        }
        {
          float s = (base + (-0x1p-25f) * acc[Mb][1][reg]) + cnv1;
          const bool better = s < mn[sl];
          const u32 curv = idp[sl >> 2];
          const u32 upd = (curv & ~(255u << sh)) | (((u32)((ct << 1) | 1)) << sh);
          idp[sl >> 2] = better ? upd : curv;
          mn[sl] = better ? s : mn[sl];
        }
      }
#pragma unroll
      for (int r = 0; r < 16; ++r) {
        acc[0][0][r] = 0.f; acc[0][1][r] = 0.f; acc[1][0][r] = 0.f; acc[1][1][r] = 0.f;
      }
    }

    __syncthreads();  // drains gll(st+1) + all reads of Bsh[cur]
  }

  // ---- final reduction: per-slot butterfly over 32 col-lanes, then cross-wave
#pragma unroll
  for (int sl = 0; sl < 32; ++sl) {
    float v = mn[sl];
    const u32 byte = (idp[sl >> 2] >> ((sl & 3) << 3)) & 255u;
    u32 code = ((byte >> 1) << 9) + ((u32)w << 6) + ((byte & 1) << 5) + (u32)col;
#pragma unroll
    for (int off = 1; off < 32; off <<= 1) {
      float v2 = __shfl_xor(v, off, 64);
      u32 c2 = (u32)__shfl_xor((int)code, off, 64);
      if (v2 < v || (v2 == v && c2 < code)) { v = v2; code = c2; }
    }
    if (col == 0) {
      const int row = ((sl >> 4) << 5) + (sl & 3) + (((sl >> 2) & 3) << 3) + (hi << 2);
      wredS[w][row] = v; wredC[w][row] = code;
    }
  }
  __syncthreads();
  if (tid < 64) {
    float bv = wredS[0][tid]; u32 bc = wredC[0][tid];
#pragma unroll
    for (int j = 1; j < 8; ++j) {
      float vv = wredS[j][tid]; u32 cc = wredC[j][tid];
      if (vv < bv || (vv == bv && cc < bc)) { bv = vv; bc = cc; }
    }
    finS[tid] = bc;
    out[(size_t)8388608 + ((size_t)b << 10) + (h0 << 5) + tid] = (float)bc;
  }
  __syncthreads();

  // ---- codes gather: out[b,c,h,w] = codebook[idx][c]
  {
    const int pt = tid & 63, cg = tid >> 6;
    const u32 code = finS[pt];
    const float4* cbr = cb4 + ((size_t)code << 6);
    const size_t obase = ((size_t)b << 18) + (h0 << 5) + pt;
#pragma unroll
    for (int cc = 0; cc < 8; ++cc) {
      const int c4 = (cc << 3) + cg;
      float4 vv = cbr[c4];
      out[obase + (size_t)((c4 << 2) + 0) * 1024] = vv.x;
      out[obase + (size_t)((c4 << 2) + 1) * 1024] = vv.y;
      out[obase + (size_t)((c4 << 2) + 2) * 1024] = vv.z;
      out[obase + (size_t)((c4 << 2) + 3) * 1024] = vv.w;
    }
  }
}

// ---------------- fallback (round-3 kernel, used only if ws too small) -------
__global__ void __launch_bounds__(512, 2) vq_fb(const float* __restrict__ x,
                                                const float4* __restrict__ cb4,
                                                const float* __restrict__ cn,
                                                float* __restrict__ out) {
  __shared__ __align__(16) _Float16 F2[2][64][264];
  __shared__ __align__(16) _Float16 Bsh[512][72];
  __shared__ float fnP[64][8];
  __shared__ float fnS[64];
  __shared__ float wredS[8][64];
  __shared__ u32  wredC[8][64];
  __shared__ u32  finS[64];

  const int tid = threadIdx.x;
  const int lane = tid & 63;
  const int w = tid >> 6;
  const int col = lane & 31;
  const int hi = lane >> 5;
  const int b = blockIdx.x >> 4;
  const int h0 = (blockIdx.x & 15) << 1;

  float4 rg[8];
  {
    const float4* src = cb4 + ((size_t)tid << 6);
#pragma unroll
    for (int j = 0; j < 8; ++j) rg[j] = src[j];
  }
  {
    const float* xb = x + ((size_t)b << 18) + (h0 << 5);
    float s = 0.f;
#pragma unroll
    for (int j = 0; j < 4; ++j) {
      v8h hv, mv;
#pragma unroll
      for (int i = 0; i < 8; ++i) {
        const int c = (w << 5) + (j << 3) + i;
        float v = xb[(size_t)c * 1024 + lane];
        s += v * v;
        float vs = v * 8192.f;
        _Float16 h = (_Float16)vs;
        _Float16 m = (_Float16)(vs - (float)h);
        hv[i] = h; mv[i] = m;
      }
      *(v8h*)&F2[0][lane][(w << 5) + (j << 3)] = hv;
      *(v8h*)&F2[1][lane][(w << 5) + (j << 3)] = mv;
    }
    fnP[lane][w] = s;
  }
  __syncthreads();
  if (tid < 64) {
    float t = 0.f;
#pragma unroll
    for (int j = 0; j < 8; ++j) t += fnP[tid][j];
    fnS[tid] = t;
  }
  {
#pragma unroll
    for (int j = 0; j < 4; ++j) {
      float t0[8] = {rg[2*j].x, rg[2*j].y, rg[2*j].z, rg[2*j].w,
                     rg[2*j+1].x, rg[2*j+1].y, rg[2*j+1].z, rg[2*j+1].w};
      v8h hv, mv;
#pragma unroll
      for (int i = 0; i < 8; ++i) {
        float vs = t0[i] * 8192.f;
        _Float16 h = (_Float16)vs;
        _Float16 m = (_Float16)(vs - (float)h);
        hv[i] = h; mv[i] = m;
      }
      *(v8h*)&Bsh[tid][(j << 3)] = hv;
      *(v8h*)&Bsh[tid][32 + (j << 3)] = mv;
    }
  }
  __syncthreads();

  float fnr[32];
#pragma unroll
  for (int sl = 0; sl < 32; ++sl) {
    const int row = ((sl >> 4) << 5) + (sl & 3) + (((sl >> 2) & 3) << 3) + (hi << 2);
    fnr[sl] = fnS[row];
  }

  f32x16 acc[2][2];
#pragma unroll
  for (int r = 0; r < 16; ++r) {
    acc[0][0][r] = 0.f; acc[0][1][r] = 0.f; acc[1][0][r] = 0.f; acc[1][1][r] = 0.f;
  }
  float mn[32];
#pragma unroll
  for (int sl = 0; sl < 32; ++sl) mn[sl] = INFINITY;
  u32 idp[8] = {0, 0, 0, 0, 0, 0, 0, 0};
  float cnv0 = 0.f, cnv1 = 0.f;

  for (int st = 0; st < 128; ++st) {
    const int ks = st & 7, ct = st >> 3;
    if (st < 127) {
      const int tn = st + 1;
      const float4* src = cb4 + ((size_t)((((tn >> 3) << 9) + tid)) << 6) + ((tn & 7) << 3);
#pragma unroll
      for (int j = 0; j < 8; ++j) rg[j] = src[j];
    }
    if (ks == 0) {
      cnv0 = cn[(ct << 9) + (w << 6) + col];
      cnv1 = cn[(ct << 9) + (w << 6) + 32 + col];
    }
    const int kb = ks << 5;
#pragma unroll
    for (int kh = 0; kh < 2; ++kh) {
      const int ko = kb + (kh << 4) + (hi << 3);
      const v8h ah0 = *(const v8h*)&F2[0][col][ko];
      const v8h ah1 = *(const v8h*)&F2[0][32 + col][ko];
      const v8h am0 = *(const v8h*)&F2[1][col][ko];
      const v8h am1 = *(const v8h*)&F2[1][32 + col][ko];
      const int bo = (kh << 4) + (hi << 3);
      const v8h bh0 = *(const v8h*)&Bsh[(w << 6) + col][bo];
      const v8h bh1 = *(const v8h*)&Bsh[(w << 6) + 32 + col][bo];
      const v8h bm0 = *(const v8h*)&Bsh[(w << 6) + col][32 + bo];
      const v8h bm1 = *(const v8h*)&Bsh[(w << 6) + 32 + col][32 + bo];
      acc[0][0] = MFMA16(ah0, bh0, acc[0][0], 0, 0, 0);
      acc[0][0] = MFMA16(ah0, bm0, acc[0][0], 0, 0, 0);
      acc[0][0] = MFMA16(am0, bh0, acc[0][0], 0, 0, 0);
      acc[0][1] = MFMA16(ah0, bh1, acc[0][1], 0, 0, 0);
      acc[0][1] = MFMA16(ah0, bm1, acc[0][1], 0, 0, 0);
      acc[0][1] = MFMA16(am0, bh1, acc[0][1], 0, 0, 0);
      acc[1][0] = MFMA16(ah1, bh0, acc[1][0], 0, 0, 0);
      acc[1][0] = MFMA16(ah1, bm0, acc[1][0], 0, 0, 0);
      acc[1][0] = MFMA16(am1, bh0, acc[1][0], 0, 0, 0);
      acc[1][1] = MFMA16(ah1, bh1, acc[1][1], 0, 0, 0);
      acc[1][1] = MFMA16(ah1, bm1, acc[1][1], 0, 0, 0);
      acc[1][1] = MFMA16(am1, bh1, acc[1][1], 0, 0, 0);
    }
    if (ks == 7) {
#pragma unroll
      for (int sl = 0; sl < 32; ++sl) {
        const int Mb = sl >> 4, reg = sl & 15;
        const float base = fnr[sl];
        const u32 sh = (u32)((sl & 3) << 3);
        {
          float s = (base + (-0x1p-25f) * acc[Mb][0][reg]) + cnv0;
          const bool better = s < mn[sl];
          const u32 curv = idp[sl >> 2];
          const u32 upd = (curv & ~(255u << sh)) | (((u32)(ct << 1)) << sh);
          idp[sl >> 2] = better ? upd : curv;
          mn[sl] = better ? s : mn[sl];
        }
        {
          float s = (base + (-0x1p-25f) * acc[Mb][1][reg]) + cnv1;
          const bool better = s < mn[sl];
          const u32 curv = idp[sl >> 2];
          const u32 upd = (curv & ~(255u << sh)) | (((u32)((ct << 1) | 1)) << sh);
          idp[sl >> 2] = better ? upd : curv;
          mn[sl] = better ? s : mn[sl];
        }
      }
#pragma unroll
      for (int r = 0; r < 16; ++r) {
        acc[0][0][r] = 0.f; acc[0][1][r] = 0.f; acc[1][0][r] = 0.f; acc[1][1][r] = 0.f;
      }
    }
    v8h cr[8];
    if (st < 127) {
#pragma unroll
      for (int j = 0; j < 4; ++j) {
        float t0[8] = {rg[2*j].x, rg[2*j].y, rg[2*j].z, rg[2*j].w,
                       rg[2*j+1].x, rg[2*j+1].y, rg[2*j+1].z, rg[2*j+1].w};
#pragma unroll
        for (int i = 0; i < 8; ++i) {
          float vs = t0[i] * 8192.f;
          _Float16 h = (_Float16)vs;
          _Float16 m = (_Float16)(vs - (float)h);
          cr[j][i] = h; cr[4 + j][i] = m;
        }
      }
    }
    __syncthreads();
    if (st < 127) {
#pragma unroll
      for (int j = 0; j < 4; ++j) {
        *(v8h*)&Bsh[tid][(j << 3)] = cr[j];
        *(v8h*)&Bsh[tid][32 + (j << 3)] = cr[4 + j];
      }
    }
    __syncthreads();
  }

#pragma unroll
  for (int sl = 0; sl < 32; ++sl) {
    float v = mn[sl];
    const u32 byte = (idp[sl >> 2] >> ((sl & 3) << 3)) & 255u;
    u32 code = ((byte >> 1) << 9) + ((u32)w << 6) + ((byte & 1) << 5) + (u32)col;
#pragma unroll
    for (int off = 1; off < 32; off <<= 1) {
      float v2 = __shfl_xor(v, off, 64);
      u32 c2 = (u32)__shfl_xor((int)code, off, 64);
      if (v2 < v || (v2 == v && c2 < code)) { v = v2; code = c2; }
    }
    if (col == 0) {
      const int row = ((sl >> 4) << 5) + (sl & 3) + (((sl >> 2) & 3) << 3) + (hi << 2);
      wredS[w][row] = v; wredC[w][row] = code;
    }
  }
  __syncthreads();
  if (tid < 64) {
    float bv = wredS[0][tid]; u32 bc = wredC[0][tid];
#pragma unroll
    for (int j = 1; j < 8; ++j) {
      float vv = wredS[j][tid]; u32 cc = wredC[j][tid];
      if (vv < bv || (vv == bv && cc < bc)) { bv = vv; bc = cc; }
    }
    finS[tid] = bc;
    out[(size_t)8388608 + ((size_t)b << 10) + (h0 << 5) + tid] = (float)bc;
  }
  __syncthreads();
  {
    const int pt = tid & 63, cg = tid >> 6;
    const u32 code = finS[pt];
    const float4* cbr = cb4 + ((size_t)code << 6);
    const size_t obase = ((size_t)b << 18) + (h0 << 5) + pt;
#pragma unroll
    for (int cc = 0; cc < 8; ++cc) {
      const int c4 = (cc << 3) + cg;
      float4 vv = cbr[c4];
      out[obase + (size_t)((c4 << 2) + 0) * 1024] = vv.x;
      out[obase + (size_t)((c4 << 2) + 1) * 1024] = vv.y;
      out[obase + (size_t)((c4 << 2) + 2) * 1024] = vv.z;
      out[obase + (size_t)((c4 << 2) + 3) * 1024] = vv.w;
    }
  }
}

extern "C" void kernel_launch(void* const* d_in, const int* in_sizes, int n_in,
                              void* d_out, int out_size, void* d_ws, size_t ws_size,
                              hipStream_t stream) {
  const float* x = (const float*)d_in[0];
  const float* cb = (const float*)d_in[1];
  float* out = (float*)d_out;
  float* cnorm = (float*)d_ws;  // 8192 floats at ws[0:32KB)

  cnorm_k<<<2048, 256, 0, stream>>>((const float4*)cb, cnorm);
  if (ws_size >= (size_t)32768 + (size_t)16777216) {
    _Float16* W = (_Float16*)((char*)d_ws + 32768);  // 16 MB split-permuted planes
    split_cb<<<1024, 256, 0, stream>>>((const float4*)cb, W);
    vq_fast<<<512, 512, 0, stream>>>(x, (const float4*)cb, cnorm, W, out);
  } else {
    vq_fb<<<512, 512, 0, stream>>>(x, (const float4*)cb, cnorm, out);
  }
}